// Round 2
// baseline (503.075 us; speedup 1.0000x reference)
//
#include <hip/hip_runtime.h>
#include <math.h>

#define RES 128

__global__ __launch_bounds__(256) void mel_kernel(
    const float* __restrict__ xyz, const float* __restrict__ l,
    const float* __restrict__ base, float* __restrict__ out, int n)
{
    int i = blockIdx.x * blockDim.x + threadIdx.x;
    if (i >= n) return;

    // ---- direction = l / max(||l||, 1e-9) ----
    float lx = l[3*i+0], ly = l[3*i+1], lz = l[3*i+2];
    float nrm = sqrtf(lx*lx + ly*ly + lz*lz);
    float inv = 1.0f / fmaxf(nrm, 1e-9f);
    float dx = lx*inv, dy = ly*inv, dz = lz*inv;

    // ---- cube face / uv (OpenGL convention) ----
    float ax = fabsf(dx), ay = fabsf(dy), az = fabsf(dz);
    bool is_x = (ax >= ay) && (ax >= az);
    bool is_y = (!is_x) && (ay >= az);

    int face;
    float ma, sc, tc;
    if (is_x) {
        face = (dx >= 0.0f) ? 0 : 1;
        ma = ax;
        sc = (dx >= 0.0f) ? -dz : dz;
        tc = -dy;
    } else if (is_y) {
        face = (dy >= 0.0f) ? 2 : 3;
        ma = ay;
        sc = dx;
        tc = (dy >= 0.0f) ? dz : -dz;
    } else {
        face = (dz >= 0.0f) ? 4 : 5;
        ma = az;
        sc = (dz >= 0.0f) ? dx : -dx;
        tc = -dy;
    }
    ma = fmaxf(ma, 1e-9f);
    float u = 0.5f * (sc / ma + 1.0f);
    float v = 0.5f * (tc / ma + 1.0f);

    // ---- bilinear tap coords on the 128x128 face ----
    float fx = u * (float)RES - 0.5f;
    float fy = v * (float)RES - 0.5f;
    float x0f = floorf(fx), y0f = floorf(fy);
    float tx = fx - x0f, ty = fy - y0f;
    int x0 = min(max((int)x0f,     0), RES-1);
    int x1 = min(max((int)x0f + 1, 0), RES-1);
    int y0 = min(max((int)y0f,     0), RES-1);
    int y1 = min(max((int)y0f + 1, 0), RES-1);

    // ---- trilinear probe corners on the (8,8,4) grid, span = 1 ----
    float px = xyz[3*i+0], py = xyz[3*i+1], pz = xyz[3*i+2];
    float cx = fminf(fmaxf(px * 7.0f, 0.0f), 7.0f);
    float cy = fminf(fmaxf(py * 7.0f, 0.0f), 7.0f);
    float cz = fminf(fmaxf(pz * 3.0f, 0.0f), 3.0f);
    int ix0 = (int)floorf(cx), iy0 = (int)floorf(cy), iz0 = (int)floorf(cz);
    int ix1 = min(ix0 + 1, 7), iy1 = min(iy0 + 1, 7), iz1 = min(iz0 + 1, 3);
    float tgx = cx - (float)ix0, tgy = cy - (float)iy0, tgz = cz - (float)iz0;

    float wx[2] = {1.0f - tgx, tgx};
    float wy[2] = {1.0f - tgy, tgy};
    float wz[2] = {1.0f - tgz, tgz};
    int   gx[2] = {ix0, ix1}, gy[2] = {iy0, iy1}, gz[2] = {iz0, iz1};

    float pw[8];
    int   pidx[8];
    float wsum = 0.0f;
    #pragma unroll
    for (int ox = 0; ox < 2; ++ox)
      #pragma unroll
      for (int oy = 0; oy < 2; ++oy)
        #pragma unroll
        for (int oz = 0; oz < 2; ++oz) {
            int p = ox*4 + oy*2 + oz;
            float w = wx[ox] * wy[oy] * wz[oz];
            pw[p]   = w;
            wsum   += w;
            pidx[p] = gx[ox]*32 + gy[oy]*4 + gz[oz];
        }
    float winv = 1.0f / fmaxf(wsum, 1e-8f);

    // ---- bilinear weights / tap offsets (texel units within a face) ----
    int t00 = y0*RES + x0;
    int t01 = y0*RES + x1;
    int t10 = y1*RES + x0;
    int t11 = y1*RES + x1;
    float bw[4];
    bw[0] = (1.0f - ty) * (1.0f - tx);
    bw[1] = (1.0f - ty) * tx;
    bw[2] = ty * (1.0f - tx);
    bw[3] = ty * tx;

    int face_off = face * (RES * RES);
    int toff[4] = {t00, t01, t10, t11};

    // ---- PHASE 1: issue ALL 96 gather loads into registers (max MLP) ----
    float vals[8][4][3];
    #pragma unroll
    for (int p = 0; p < 8; ++p) {
        const float* bp = base + (size_t)(pidx[p] * (6 * RES * RES) + face_off) * 3;
        #pragma unroll
        for (int t = 0; t < 4; ++t) {
            const float* a = bp + toff[t] * 3;
            vals[p][t][0] = a[0];
            vals[p][t][1] = a[1];
            vals[p][t][2] = a[2];
        }
    }

    // ---- PHASE 2: blend ----
    float acc0 = 0.0f, acc1 = 0.0f, acc2 = 0.0f;
    #pragma unroll
    for (int p = 0; p < 8; ++p) {
        float w = pw[p];
        #pragma unroll
        for (int t = 0; t < 4; ++t) {
            float wt = w * bw[t];
            acc0 += wt * vals[p][t][0];
            acc1 += wt * vals[p][t][1];
            acc2 += wt * vals[p][t][2];
        }
    }
    acc0 *= winv; acc1 *= winv; acc2 *= winv;

    // ---- sigmoid * 10 ----
    float s0 = 10.0f / (1.0f + __expf(-acc0));
    float s1 = 10.0f / (1.0f + __expf(-acc1));
    float s2 = 10.0f / (1.0f + __expf(-acc2));

    out[3*i+0] = s0;
    out[3*i+1] = s1;
    out[3*i+2] = s2;
}

extern "C" void kernel_launch(void* const* d_in, const int* in_sizes, int n_in,
                              void* d_out, int out_size, void* d_ws, size_t ws_size,
                              hipStream_t stream) {
    const float* xyz  = (const float*)d_in[0];
    const float* l    = (const float*)d_in[1];
    const float* base = (const float*)d_in[2];
    float* out = (float*)d_out;
    int n = in_sizes[0] / 3;
    int blocks = (n + 255) / 256;
    mel_kernel<<<blocks, 256, 0, stream>>>(xyz, l, base, out, n);
}

// Round 3
// 501.770 us; speedup vs baseline: 1.0026x; 1.0026x over previous
//
#include <hip/hip_runtime.h>
#include <math.h>

#define RES 128

__global__ __launch_bounds__(256) void mel_kernel(
    const float* __restrict__ xyz, const float* __restrict__ l,
    const float* __restrict__ base, float* __restrict__ out, int n)
{
    int i = blockIdx.x * blockDim.x + threadIdx.x;
    if (i >= n) return;

    // ---- direction = l / max(||l||, 1e-9) ----
    float lx = l[3*i+0], ly = l[3*i+1], lz = l[3*i+2];
    float nrm = sqrtf(lx*lx + ly*ly + lz*lz);
    float inv = 1.0f / fmaxf(nrm, 1e-9f);
    float dx = lx*inv, dy = ly*inv, dz = lz*inv;

    // ---- cube face / uv (OpenGL convention) ----
    float ax = fabsf(dx), ay = fabsf(dy), az = fabsf(dz);
    bool is_x = (ax >= ay) && (ax >= az);
    bool is_y = (!is_x) && (ay >= az);

    int face;
    float ma, sc, tc;
    if (is_x) {
        face = (dx >= 0.0f) ? 0 : 1;
        ma = ax;
        sc = (dx >= 0.0f) ? -dz : dz;
        tc = -dy;
    } else if (is_y) {
        face = (dy >= 0.0f) ? 2 : 3;
        ma = ay;
        sc = dx;
        tc = (dy >= 0.0f) ? dz : -dz;
    } else {
        face = (dz >= 0.0f) ? 4 : 5;
        ma = az;
        sc = (dz >= 0.0f) ? dx : -dx;
        tc = -dy;
    }
    ma = fmaxf(ma, 1e-9f);
    float u = 0.5f * (sc / ma + 1.0f);
    float v = 0.5f * (tc / ma + 1.0f);

    // ---- bilinear tap coords on the 128x128 face ----
    float fx = u * (float)RES - 0.5f;
    float fy = v * (float)RES - 0.5f;
    float x0f = floorf(fx), y0f = floorf(fy);
    float tx = fx - x0f, ty = fy - y0f;
    int x0 = min(max((int)x0f,     0), RES-1);
    int x1 = min(max((int)x0f + 1, 0), RES-1);
    int y0 = min(max((int)y0f,     0), RES-1);
    int y1 = min(max((int)y0f + 1, 0), RES-1);

    // ---- trilinear probe corners on the (8,8,4) grid, span = 1 ----
    float px = xyz[3*i+0], py = xyz[3*i+1], pz = xyz[3*i+2];
    float cx = fminf(fmaxf(px * 7.0f, 0.0f), 7.0f);
    float cy = fminf(fmaxf(py * 7.0f, 0.0f), 7.0f);
    float cz = fminf(fmaxf(pz * 3.0f, 0.0f), 3.0f);
    int ix0 = (int)floorf(cx), iy0 = (int)floorf(cy), iz0 = (int)floorf(cz);
    int ix1 = min(ix0 + 1, 7), iy1 = min(iy0 + 1, 7), iz1 = min(iz0 + 1, 3);
    float tgx = cx - (float)ix0, tgy = cy - (float)iy0, tgz = cz - (float)iz0;

    float wx[2] = {1.0f - tgx, tgx};
    float wy[2] = {1.0f - tgy, tgy};
    float wz[2] = {1.0f - tgz, tgz};
    int   gx[2] = {ix0, ix1}, gy[2] = {iy0, iy1}, gz[2] = {iz0, iz1};

    float pw[8];
    int   pidx[8];
    float wsum = 0.0f;
    #pragma unroll
    for (int ox = 0; ox < 2; ++ox)
      #pragma unroll
      for (int oy = 0; oy < 2; ++oy)
        #pragma unroll
        for (int oz = 0; oz < 2; ++oz) {
            int p = ox*4 + oy*2 + oz;
            float w = wx[ox] * wy[oy] * wz[oz];
            pw[p]   = w;
            wsum   += w;
            pidx[p] = gx[ox]*32 + gy[oy]*4 + gz[oz];
        }
    float winv = 1.0f / fmaxf(wsum, 1e-8f);

    // ---- bilinear weights / tap offsets (texel units within a face) ----
    int t00 = y0*RES + x0;
    int t01 = y0*RES + x1;
    int t10 = y1*RES + x0;
    int t11 = y1*RES + x1;
    float bw[4];
    bw[0] = (1.0f - ty) * (1.0f - tx);
    bw[1] = (1.0f - ty) * tx;
    bw[2] = ty * (1.0f - tx);
    bw[3] = ty * tx;

    int face_off = face * (RES * RES);
    int toff[4] = {t00, t01, t10, t11};

    // ---- PHASE 1: issue ALL 96 gather loads into registers (max MLP) ----
    float vals[8][4][3];
    #pragma unroll
    for (int p = 0; p < 8; ++p) {
        const float* bp = base + (size_t)(pidx[p] * (6 * RES * RES) + face_off) * 3;
        #pragma unroll
        for (int t = 0; t < 4; ++t) {
            const float* a = bp + toff[t] * 3;
            vals[p][t][0] = a[0];
            vals[p][t][1] = a[1];
            vals[p][t][2] = a[2];
        }
    }

    // Hard scheduling fence: nothing may cross (mask 0). Prevents the
    // machine scheduler from sinking the gathers back next to their uses,
    // which is what kept VGPR=36 / ~4 loads in flight in rounds 0-1.
    __builtin_amdgcn_sched_barrier(0);

    // ---- PHASE 2: blend ----
    float acc0 = 0.0f, acc1 = 0.0f, acc2 = 0.0f;
    #pragma unroll
    for (int p = 0; p < 8; ++p) {
        float w = pw[p];
        #pragma unroll
        for (int t = 0; t < 4; ++t) {
            float wt = w * bw[t];
            acc0 += wt * vals[p][t][0];
            acc1 += wt * vals[p][t][1];
            acc2 += wt * vals[p][t][2];
        }
    }
    acc0 *= winv; acc1 *= winv; acc2 *= winv;

    // ---- sigmoid * 10 ----
    float s0 = 10.0f / (1.0f + __expf(-acc0));
    float s1 = 10.0f / (1.0f + __expf(-acc1));
    float s2 = 10.0f / (1.0f + __expf(-acc2));

    out[3*i+0] = s0;
    out[3*i+1] = s1;
    out[3*i+2] = s2;
}

extern "C" void kernel_launch(void* const* d_in, const int* in_sizes, int n_in,
                              void* d_out, int out_size, void* d_ws, size_t ws_size,
                              hipStream_t stream) {
    const float* xyz  = (const float*)d_in[0];
    const float* l    = (const float*)d_in[1];
    const float* base = (const float*)d_in[2];
    float* out = (float*)d_out;
    int n = in_sizes[0] / 3;
    int blocks = (n + 255) / 256;
    mel_kernel<<<blocks, 256, 0, stream>>>(xyz, l, base, out, n);
}